// Round 18
// baseline (70.276 us; speedup 1.0000x reference)
//
#include <hip/hip_runtime.h>
#include <math.h>

#define N_NODES 8192
#define N_EDGES 262144
#define NFEAT 128
#define NHID 256
#define NCLASS 16
#define ELLS 96   // ELL stride; P(Poisson(32) >= 96) ~ 1e-18 per row

// LESSON (round 13): grid.sync() mega-kernel = ~58 us PER SYNC at 512 blocks. Never.
// LESSON (round 15): dependent loads (deg[c]) in the gather staging chain cost
// ~10 us. Normalization stays pre-folded: xs carries di[c], V2s carries di[c].
// LESSON (round 17): staging width & occupancy are NOT the lever (59.3-59.7 flat).
// This round: wave-uniform rows + readfirstlane -> scalar (s_load) ELL staging,
// removing all DS-broadcast ops from the gather inner loops.

// f32 -> bf16 with round-to-nearest-even
__device__ inline unsigned int f2bf(float f) {
    unsigned int u = __float_as_uint(f);
    u += 0x7fffu + ((u >> 16) & 1u);
    return u >> 16;
}
__device__ inline float bf_lo(unsigned int u) { return __uint_as_float(u << 16); }
__device__ inline float bf_hi(unsigned int u) { return __uint_as_float(u & 0xffff0000u); }

// ---------------- zero cnt (32 KB) ----------------
__global__ void zero_kernel(int* __restrict__ p) {
    p[blockIdx.x * 256 + threadIdx.x] = 0;   // 32 blocks x 256 = 8192 words
}

// ---------------- one pass over edges: count + ELL store (raw weight) ----------------
__global__ __launch_bounds__(256) void histscatter_kernel(const int* __restrict__ ei,
                                                          const float* __restrict__ ew,
                                                          int* __restrict__ cnt,
                                                          int2* __restrict__ ell) {
    int e = blockIdx.x * 256 + threadIdx.x;     // 1024 blocks == E exactly
    int r = ei[e];
    int c = ei[N_EDGES + e];
    float w = ew[e];
    int slot = atomicAdd(&cnt[r], 1);
    ell[r * ELLS + slot] = make_int2(c, __float_as_int(w));
}

// ---------------- per row: deg, dinv, xs = bf16(dinv*x). 8 rows/block, 32 lanes/row ----------------
__global__ __launch_bounds__(256) void dinvcvt_kernel(const int* __restrict__ cnt,
                                                      const int2* __restrict__ ell,
                                                      const float* __restrict__ x,
                                                      float* __restrict__ dinv,
                                                      uint2* __restrict__ xs) {
    int t = threadIdx.x;
    int lane = t & 31;
    int r = blockIdx.x * 8 + (t >> 5);          // 1024 blocks
    int n = cnt[r];
    float sum = 0.0f;
    for (int base = 0; base < n; base += 32) {
        int idx = base + lane;
        if (idx < n) sum += __int_as_float(ell[r * ELLS + idx].y);
    }
    #pragma unroll
    for (int off = 1; off < 32; off <<= 1) sum += __shfl_xor(sum, off, 32);
    float di = rsqrtf(sum + 1.0f);              // + self loop, always >= 1
    if (lane == 0) dinv[r] = di;
    float4 a = ((const float4*)(x + (size_t)r * NFEAT + lane * 4))[0];
    uint2 o;
    o.x = f2bf(di * a.x) | (f2bf(di * a.y) << 16);
    o.y = f2bf(di * a.z) | (f2bf(di * a.w) << 16);
    xs[r * 32 + lane] = o;
}

// ---------------- fused: gather -> AX -> H=relu(AX@W1+b1) -> V2s=dinv*(H@W2) ----------------
// 512 threads, 8 rows/block, ONE ROW PER WAVE (64 lanes), 1024 blocks.
// Wave-uniform r via readfirstlane -> ELL entries come in as s_load / SGPRs:
// inner loop is global_load(saddr) + 2 v_fmac, no DS ops.
__global__ __launch_bounds__(512) void layer12_kernel(const int* __restrict__ cnt,
                                                      const int2* __restrict__ ell,
                                                      const unsigned int* __restrict__ xs1,
                                                      const float* __restrict__ dinv,
                                                      const float* __restrict__ W1,
                                                      const float* __restrict__ b1,
                                                      const float* __restrict__ W2,
                                                      float* __restrict__ V2s) {
    __shared__ float axs[8][NFEAT];        // 4 KB
    __shared__ float psum[8][NHID];        // 8 KB
    __shared__ float hs[8][NHID + 4];      // 8.125 KB
    __shared__ float part[512];            // 2 KB
    int t = threadIdx.x;

    // ---- phase A: acc = xs[r] + sum w*xs[c]; AX = dinv[r]*acc. 2 bf16/lane.
    int lane = t & 63;
    int rloc = t >> 6;
    int r_u = __builtin_amdgcn_readfirstlane(blockIdx.x * 8 + rloc);
    int n = cnt[r_u];
    float di = dinv[r_u];
    const int2* __restrict__ row = ell + (size_t)r_u * ELLS;
    unsigned int xv = xs1[r_u * 64 + lane];
    float acc0 = bf_lo(xv), acc1 = bf_hi(xv);   // self (xs already dinv-scaled)
    for (int base = 0; base < n; base += 8) {
        #pragma unroll
        for (int u = 0; u < 8; ++u) {
            int idx = base + u;
            int2 cw = row[idx];                          // uniform -> s_load
            int c = cw.x & (N_NODES - 1);                // clamp garbage tail
            float w = (idx < n) ? __int_as_float(cw.y) : 0.0f;  // s_cselect
            unsigned int v = xs1[c * 64 + lane];         // saddr + 4*lane
            acc0 += w * bf_lo(v);
            acc1 += w * bf_hi(v);
        }
    }
    ((float2*)&axs[rloc][lane * 2])[0] = make_float2(di * acc0, di * acc1);
    __syncthreads();

    // ---- phase B: k-split halves. col = t&255, kh = t>>8.
    int col = t & 255;
    int kh = t >> 8;
    float hacc[8];
    #pragma unroll
    for (int q = 0; q < 8; ++q) hacc[q] = 0.0f;
    int k0 = kh * 64;
    #pragma unroll 4
    for (int k = k0; k < k0 + 64; ++k) {
        float w = W1[k * NHID + col];
        #pragma unroll
        for (int q = 0; q < 8; ++q) hacc[q] += axs[q][k] * w;
    }
    if (kh == 0) {
        #pragma unroll
        for (int q = 0; q < 8; ++q) psum[q][col] = hacc[q];
    }
    __syncthreads();
    if (kh == 1) {
        float bb = b1[col];
        #pragma unroll
        for (int q = 0; q < 8; ++q) {
            float v = psum[q][col] + hacc[q] + bb;
            hs[q][col] = v > 0.0f ? v : 0.0f;
        }
    }
    __syncthreads();

    // ---- phase C: V2s[r][j] = dinv[r] * sum_k hs[r][k] * W2[k][j]; k-split x4.
    int j = t & 15;
    int rq = (t >> 4) & 7;
    int kb = (t >> 7) * 64;                     // 4 quarters of 64
    float p = 0.0f;
    #pragma unroll 8
    for (int k = 0; k < 64; ++k) p += hs[rq][kb + k] * W2[(kb + k) * NCLASS + j];
    part[t] = p;
    __syncthreads();
    if (t < 128) {
        int rg = blockIdx.x * 8 + (t >> 4);
        V2s[rg * NCLASS + (t & 15)] =
            dinv[rg] * (part[t] + part[t + 128] + part[t + 256] + part[t + 384]);
    }
}

// ---------------- out[r] = log_softmax(dinv[r]*(V2s[r] + sum w*V2s[c]) + b2) ----------------
// ONE ROW PER WAVE (4 rows/block, 2048 blocks). Scalar ELL staging; all four
// 16-lane groups compute identical values on broadcast addresses (no divergence,
// one memory request). V2s already carries di[c]; weights RAW (round-14 lesson).
__global__ __launch_bounds__(256) void agg2_kernel(const int* __restrict__ cnt,
                                                   const int2* __restrict__ ell,
                                                   const float* __restrict__ V2s,
                                                   const float* __restrict__ dinv,
                                                   const float* __restrict__ b2,
                                                   float* __restrict__ out) {
    int t = threadIdx.x;
    int lane = t & 63;
    int j = lane & 15;                // class (4 redundant groups)
    int r_u = __builtin_amdgcn_readfirstlane(blockIdx.x * 4 + (t >> 6));
    int n = cnt[r_u];
    float di = dinv[r_u];
    const int2* __restrict__ row = ell + (size_t)r_u * ELLS;
    float acc = V2s[r_u * NCLASS + j];   // self term (V2s already dinv-scaled)
    for (int base = 0; base < n; base += 8) {
        #pragma unroll
        for (int u = 0; u < 8; ++u) {
            int idx = base + u;
            int2 cw = row[idx];                          // uniform -> s_load
            int c = cw.x & (N_NODES - 1);
            float w = (idx < n) ? __int_as_float(cw.y) : 0.0f;
            acc += w * V2s[c * NCLASS + j];              // saddr + 4*j broadcast
        }
    }
    float v = di * acc + b2[j];
    // log_softmax across the 16 lanes of each group
    float mx = v;
    #pragma unroll
    for (int off = 1; off < 16; off <<= 1) mx = fmaxf(mx, __shfl_xor(mx, off));
    float ex = expf(v - mx);
    float ssum = ex;
    #pragma unroll
    for (int off = 1; off < 16; off <<= 1) ssum += __shfl_xor(ssum, off);
    if (lane < 16) out[r_u * NCLASS + j] = v - mx - logf(ssum);
}

extern "C" void kernel_launch(void* const* d_in, const int* in_sizes, int n_in,
                              void* d_out, int out_size, void* d_ws, size_t ws_size,
                              hipStream_t stream) {
    const float* x  = (const float*)d_in[0];
    const int*   ei = (const int*)d_in[1];      // [2, E] flat: row = ei[e], col = ei[E+e]
    const float* ew = (const float*)d_in[2];
    const float* W1 = (const float*)d_in[3];
    const float* b1 = (const float*)d_in[4];
    const float* W2 = (const float*)d_in[5];
    const float* b2 = (const float*)d_in[6];
    float* out = (float*)d_out;

    const int n = N_NODES;

    char* ws = (char*)d_ws;
    int*   cnt  = (int*)  (ws);                  // [0, 32K)
    float* dinv = (float*)(ws + 32768);          // [32K, 64K)
    int2*  ell  = (int2*) (ws + 65536);          // [64K, 64K+6M): 8192*96*8 B
    float* V2s  = (float*)(ws + 8388608);        // [8M, 8.5M)
    uint2* xs   = (uint2*)(ws + 16777216);       // [16M, 18M): bf16 dinv-scaled x

    zero_kernel<<<32, 256, 0, stream>>>(cnt);

    histscatter_kernel<<<N_EDGES / 256, 256, 0, stream>>>(ei, ew, cnt, ell);
    dinvcvt_kernel<<<n / 8, 256, 0, stream>>>(cnt, ell, x, dinv, xs);

    layer12_kernel<<<n / 8, 512, 0, stream>>>(cnt, ell, (const unsigned int*)xs,
                                              dinv, W1, b1, W2, V2s);
    agg2_kernel<<<n / 4, 256, 0, stream>>>(cnt, ell, V2s, dinv, b2, out);
}

// Round 19
// 66.108 us; speedup vs baseline: 1.0631x; 1.0631x over previous
//
#include <hip/hip_runtime.h>
#include <math.h>

#define N_NODES 8192
#define N_EDGES 262144
#define NFEAT 128
#define NHID 256
#define NCLASS 16
#define ELLS 96   // ELL stride; P(Poisson(32) >= 96) ~ 1e-18 per row

// LESSON (round 13): grid.sync() mega-kernel = ~58 us PER SYNC. Never.
// LESSON (round 15): dependent deg[c] loads inside the gather chain cost ~10 us.
// LESSON (round 18): readfirstlane/scalar ELL staging serializes; vector loads win.
// This round: per-row LDS edge table with fully-normalized weights
// (w' = di_r*w*di_c, built ONCE per row with parallel deg[c] reads), so both
// gathers use raw features and the inner loop is LDS-broadcast + load + FMA.

// f32 -> bf16 with round-to-nearest-even
__device__ inline unsigned int f2bf(float f) {
    unsigned int u = __float_as_uint(f);
    u += 0x7fffu + ((u >> 16) & 1u);
    return u >> 16;
}
__device__ inline float bf_lo(unsigned int u) { return __uint_as_float(u << 16); }
__device__ inline float bf_hi(unsigned int u) { return __uint_as_float(u & 0xffff0000u); }

// ---------------- zero deg + cnt (64 KB) ----------------
__global__ void zero_kernel(int* __restrict__ p) {
    p[blockIdx.x * 256 + threadIdx.x] = 0;   // 64 blocks x 256 = 16384 words
}

// ---- blocks [0,1024): edges -> ELL + deg/cnt atomics; [1024,1536): xs = bf16(raw x) ----
__global__ __launch_bounds__(256) void histscatter_kernel(const int* __restrict__ ei,
                                                          const float* __restrict__ ew,
                                                          const float* __restrict__ x,
                                                          float* __restrict__ deg,
                                                          int* __restrict__ cnt,
                                                          int2* __restrict__ ell,
                                                          uint4* __restrict__ xb4) {
    int t = threadIdx.x;
    int b = blockIdx.x;
    if (b < 1024) {
        int e = b * 256 + t;                  // 1024*256 == E exactly
        int r = ei[e];
        int c = ei[N_EDGES + e];
        float w = ew[e];
        atomicAdd(&deg[r], w);
        int slot = atomicAdd(&cnt[r], 1);
        ell[r * ELLS + slot] = make_int2(c, __float_as_int(w));
    } else {
        int idx = ((b - 1024) * 256 + t) * 8; // 512*256*8 == N*NFEAT exactly
        float4 a = ((const float4*)(x + idx))[0];
        float4 c4 = ((const float4*)(x + idx))[1];
        uint4 o;
        o.x = f2bf(a.x) | (f2bf(a.y) << 16);
        o.y = f2bf(a.z) | (f2bf(a.w) << 16);
        o.z = f2bf(c4.x) | (f2bf(c4.y) << 16);
        o.w = f2bf(c4.z) | (f2bf(c4.w) << 16);
        xb4[idx >> 3] = o;
    }
}

// ---------------- fused: LDS edge table -> gather -> AX -> H -> V2 = H@W2 (raw) ----------------
// 512 threads, 8 rows/block (one row per wave), 1024 blocks. LDS ~28.2 KB -> 4 blocks/CU.
__global__ __launch_bounds__(512) void layer12_kernel(const float* __restrict__ deg,
                                                      const int* __restrict__ cnt,
                                                      const int2* __restrict__ ell,
                                                      const unsigned int* __restrict__ xs1,
                                                      const float* __restrict__ W1,
                                                      const float* __restrict__ b1,
                                                      const float* __restrict__ W2,
                                                      float* __restrict__ V2) {
    __shared__ int2  cwl[8][ELLS];         // 6 KB: per-row normalized edge table
    __shared__ float axs[8][NFEAT];        // 4 KB
    __shared__ float psum[8][NHID];        // 8 KB
    __shared__ float hs[8][NHID + 4];      // 8.125 KB
    __shared__ float part[512];            // 2 KB
    int t = threadIdx.x;

    // ---- prologue: build (c, w'=di_r*w*di_c) in LDS; pad to x8 with w'=0 ----
    int lane = t & 63;
    int rloc = t >> 6;
    int r = blockIdx.x * 8 + rloc;
    int n = cnt[r];
    float dr = rsqrtf(deg[r] + 1.0f);      // + self loop, always >= 1
    int npad = (n + 7) & ~7;
    for (int idx = lane; idx < npad; idx += 64) {
        int2 cw = ell[r * ELLS + idx];
        int c = cw.x & (N_NODES - 1);
        float w = 0.0f;
        if (idx < n) w = __int_as_float(cw.y) * dr * rsqrtf(deg[c] + 1.0f);
        cwl[rloc][idx] = make_int2((idx < n) ? c : 0, __float_as_int(w));
    }
    // same wave writes & reads its row's table: no barrier needed.

    // ---- phase A: AX[r] = dr^2*x[r] + sum w'*x[c]; 2 bf16/lane ----
    unsigned int xv = xs1[r * 64 + lane];
    float c0 = dr * dr;
    float acc0 = c0 * bf_lo(xv), acc1 = c0 * bf_hi(xv);
    for (int base = 0; base < npad; base += 8) {
        #pragma unroll
        for (int u = 0; u < 8; ++u) {
            int2 cw = cwl[rloc][base + u];           // LDS broadcast
            float w = __int_as_float(cw.y);
            unsigned int v = xs1[cw.x * 64 + lane];
            acc0 += w * bf_lo(v);
            acc1 += w * bf_hi(v);
        }
    }
    ((float2*)&axs[rloc][lane * 2])[0] = make_float2(acc0, acc1);
    __syncthreads();

    // ---- phase B: hs = relu(AX@W1 + b1); k-split halves ----
    int col = t & 255;
    int kh = t >> 8;
    float hacc[8];
    #pragma unroll
    for (int q = 0; q < 8; ++q) hacc[q] = 0.0f;
    int k0 = kh * 64;
    #pragma unroll 4
    for (int k = k0; k < k0 + 64; ++k) {
        float w = W1[k * NHID + col];
        #pragma unroll
        for (int q = 0; q < 8; ++q) hacc[q] += axs[q][k] * w;
    }
    if (kh == 0) {
        #pragma unroll
        for (int q = 0; q < 8; ++q) psum[q][col] = hacc[q];
    }
    __syncthreads();
    if (kh == 1) {
        float bb = b1[col];
        #pragma unroll
        for (int q = 0; q < 8; ++q) {
            float v = psum[q][col] + hacc[q] + bb;
            hs[q][col] = v > 0.0f ? v : 0.0f;
        }
    }
    __syncthreads();

    // ---- phase C: V2[r][j] = sum_k hs[r][k] * W2[k][j] (RAW, no dinv); k-split x4 ----
    int j = t & 15;
    int rq = (t >> 4) & 7;
    int kb = (t >> 7) * 64;
    float p = 0.0f;
    #pragma unroll 8
    for (int k = 0; k < 64; ++k) p += hs[rq][kb + k] * W2[(kb + k) * NCLASS + j];
    part[t] = p;
    __syncthreads();
    if (t < 128) {
        int rg = blockIdx.x * 8 + (t >> 4);
        V2[rg * NCLASS + (t & 15)] =
            part[t] + part[t + 128] + part[t + 256] + part[t + 384];
    }
}

// ---------------- out[r] = log_softmax(dr^2*V2[r] + sum w'*V2[c] + b2) ----------------
// 8 rows/block, 32 lanes/row (two 16-lane groups on alternate 8-chunks), 1024 blocks.
__global__ __launch_bounds__(256) void agg2_kernel(const float* __restrict__ deg,
                                                   const int* __restrict__ cnt,
                                                   const int2* __restrict__ ell,
                                                   const float* __restrict__ V2,
                                                   const float* __restrict__ b2,
                                                   float* __restrict__ out) {
    __shared__ int2 cwl[8][ELLS];          // 6 KB
    int t = threadIdx.x;
    int lane = t & 31;
    int rloc = t >> 5;
    int r = blockIdx.x * 8 + rloc;
    int n = cnt[r];
    float dr = rsqrtf(deg[r] + 1.0f);
    int npad = (n + 7) & ~7;
    for (int idx = lane; idx < npad; idx += 32) {
        int2 cw = ell[r * ELLS + idx];
        int c = cw.x & (N_NODES - 1);
        float w = 0.0f;
        if (idx < n) w = __int_as_float(cw.y) * dr * rsqrtf(deg[c] + 1.0f);
        cwl[rloc][idx] = make_int2((idx < n) ? c : 0, __float_as_int(w));
    }
    // same wave writes & reads its rows' tables (rows rloc covered by this wave's
    // lanes only when 2 rows/wave) -- here 2 rows per 64-lane wave, both written
    // by their own 32-lane half; no cross-half reads => no barrier needed.

    int g = lane >> 4;                // half: alternate 8-chunks
    int j = lane & 15;                // class
    float acc = (g == 0) ? dr * dr * V2[r * NCLASS + j] : 0.0f;
    for (int base = g * 8; base < npad; base += 16) {
        #pragma unroll
        for (int u = 0; u < 8; ++u) {
            int2 cw = cwl[rloc][base + u];           // LDS broadcast
            float w = __int_as_float(cw.y);
            acc += w * V2[cw.x * NCLASS + j];
        }
    }
    acc += __shfl_xor(acc, 16, 32);   // combine the two chunk-groups
    float v = acc + b2[j];
    // log_softmax across 16 lanes (both halves hold identical values)
    float mx = v;
    #pragma unroll
    for (int off = 1; off < 16; off <<= 1) mx = fmaxf(mx, __shfl_xor(mx, off));
    float ex = expf(v - mx);
    float ssum = ex;
    #pragma unroll
    for (int off = 1; off < 16; off <<= 1) ssum += __shfl_xor(ssum, off);
    if (g == 0) out[r * NCLASS + j] = v - mx - logf(ssum);
}

extern "C" void kernel_launch(void* const* d_in, const int* in_sizes, int n_in,
                              void* d_out, int out_size, void* d_ws, size_t ws_size,
                              hipStream_t stream) {
    const float* x  = (const float*)d_in[0];
    const int*   ei = (const int*)d_in[1];      // [2, E] flat: row = ei[e], col = ei[E+e]
    const float* ew = (const float*)d_in[2];
    const float* W1 = (const float*)d_in[3];
    const float* b1 = (const float*)d_in[4];
    const float* W2 = (const float*)d_in[5];
    const float* b2 = (const float*)d_in[6];
    float* out = (float*)d_out;

    const int n = N_NODES;

    char* ws = (char*)d_ws;
    float* deg  = (float*)(ws);                  // [0, 32K)
    int*   cnt  = (int*)  (ws + 32768);          // [32K, 64K)
    int2*  ell  = (int2*) (ws + 65536);          // [64K, 64K+6M): 8192*96*8 B
    float* V2   = (float*)(ws + 8388608);        // [8M, 8.5M)
    uint4* xs   = (uint4*)(ws + 16777216);       // [16M, 18M): bf16 raw x

    zero_kernel<<<64, 256, 0, stream>>>((int*)ws);   // deg + cnt

    histscatter_kernel<<<1536, 256, 0, stream>>>(ei, ew, x, deg, cnt, ell, xs);

    layer12_kernel<<<n / 8, 512, 0, stream>>>(deg, cnt, ell, (const unsigned int*)xs,
                                              W1, b1, W2, V2);
    agg2_kernel<<<n / 8, 256, 0, stream>>>(deg, cnt, ell, V2, b2, out);
}

// Round 20
// 59.968 us; speedup vs baseline: 1.1719x; 1.1024x over previous
//
#include <hip/hip_runtime.h>
#include <math.h>

#define N_NODES 8192
#define N_EDGES 262144
#define NFEAT 128
#define NHID 256
#define NCLASS 16
#define ELLS 96   // ELL stride; P(Poisson(32) >= 96) ~ 1e-18 per row

// LESSON (round 13): grid.sync() mega-kernel = ~58 us PER SYNC at 512 blocks. Never.
// LESSON (round 15/19): deg[c]-dependent normalization near the gather path loses
// ~7-12 us, whether in-chain or in a parallel LDS prologue. Keep it pre-folded:
// dinvcvt scales xs by di[c] once per node; V2s carries di[c] for layer 2.
// LESSON (round 17): staging width & occupancy are not the lever (59.3-59.7 flat).
// LESSON (round 18): readfirstlane/scalar ELL staging serializes; vector loads win.
// Round 16 config = session best (59.3 us). This is that kernel, verbatim.

// f32 -> bf16 with round-to-nearest-even
__device__ inline unsigned int f2bf(float f) {
    unsigned int u = __float_as_uint(f);
    u += 0x7fffu + ((u >> 16) & 1u);
    return u >> 16;
}

#define CVT4(v, f) { \
    f[0] = __uint_as_float((v).x << 16); f[1] = __uint_as_float((v).x & 0xffff0000u); \
    f[2] = __uint_as_float((v).y << 16); f[3] = __uint_as_float((v).y & 0xffff0000u); }

// ---------------- zero cnt (32 KB) ----------------
__global__ void zero_kernel(int* __restrict__ p) {
    p[blockIdx.x * 256 + threadIdx.x] = 0;   // 32 blocks x 256 = 8192 words
}

// ---------------- one pass over edges: count + ELL store (raw weight) ----------------
__global__ __launch_bounds__(256) void histscatter_kernel(const int* __restrict__ ei,
                                                          const float* __restrict__ ew,
                                                          int* __restrict__ cnt,
                                                          int2* __restrict__ ell) {
    int e = blockIdx.x * 256 + threadIdx.x;     // 1024 blocks == E exactly
    int r = ei[e];
    int c = ei[N_EDGES + e];
    float w = ew[e];
    int slot = atomicAdd(&cnt[r], 1);
    ell[r * ELLS + slot] = make_int2(c, __float_as_int(w));
}

// ---------------- per row: deg = sum(ell w), dinv = rsqrt(deg+1), xs = bf16(dinv*x) ----------------
// 16 rows/block, 16 lanes/row. No atomics: reads the ELL row it owns.
__global__ __launch_bounds__(256) void dinvcvt_kernel(const int* __restrict__ cnt,
                                                      const int2* __restrict__ ell,
                                                      const float* __restrict__ x,
                                                      float* __restrict__ dinv,
                                                      uint4* __restrict__ xs) {
    int t = threadIdx.x;
    int j = t & 15;
    int r = blockIdx.x * 16 + (t >> 4);
    int n = cnt[r];
    float sum = 0.0f;
    for (int base = 0; base < n; base += 16) {
        int idx = base + j;
        if (idx < n) sum += __int_as_float(ell[r * ELLS + idx].y);
    }
    #pragma unroll
    for (int off = 1; off < 16; off <<= 1) sum += __shfl_xor(sum, off, 16);
    float di = rsqrtf(sum + 1.0f);              // + self loop, always >= 1
    if (j == 0) dinv[r] = di;
    const float4* xp = (const float4*)(x + (size_t)r * NFEAT + j * 8);
    float4 a = xp[0], b = xp[1];
    uint4 o;
    o.x = f2bf(di * a.x) | (f2bf(di * a.y) << 16);
    o.y = f2bf(di * a.z) | (f2bf(di * a.w) << 16);
    o.z = f2bf(di * b.x) | (f2bf(di * b.y) << 16);
    o.w = f2bf(di * b.z) | (f2bf(di * b.w) << 16);
    xs[r * 16 + j] = o;
}

// ---------------- fused: ELL gather on xs -> AX -> H=relu(AX@W1+b1) -> V2s=dinv*(H@W2) ----------------
// 8 rows/block, 1024 blocks, 32 lanes/row. LDS ~13.2 KB -> high occupancy.
// 16-wide staging chunks: one coalesced ELL load feeds 16 broadcast iterations.
__global__ __launch_bounds__(256) void layer12_kernel(const int* __restrict__ cnt,
                                                      const int2* __restrict__ ell,
                                                      const uint2* __restrict__ xs2,
                                                      const float* __restrict__ dinv,
                                                      const float* __restrict__ W1,
                                                      const float* __restrict__ b1,
                                                      const float* __restrict__ W2,
                                                      float* __restrict__ V2s) {
    __shared__ float axs[8][NFEAT];        // 4 KB
    __shared__ float hs[8][NHID + 4];      // 8.125 KB
    __shared__ float part[256];            // 1 KB
    int t = threadIdx.x;

    // ---- phase A: acc = xs[r] + sum w*xs[c]; AX = dinv[r]*acc
    int lane = t & 31;
    int rloc = t >> 5;
    int r = blockIdx.x * 8 + rloc;
    int n = cnt[r];
    float di = dinv[r];
    uint2 xv = xs2[r * 32 + lane];
    float acc[4];
    CVT4(xv, acc);                          // self term (xs already dinv-scaled)
    for (int base = 0; base < n; base += 16) {
        int idx = base + (lane & 15);
        int2 cw = ell[r * ELLS + idx];
        int cc = cw.x & (N_NODES - 1);                 // clamp garbage tail
        float wl = __int_as_float(cw.y);
        wl = (idx < n) ? wl : 0.0f;                    // mask folded pre-broadcast
        #pragma unroll
        for (int u = 0; u < 16; ++u) {
            int c = __shfl(cc, u, 16);
            float w = __shfl(wl, u, 16);
            uint2 v = xs2[c * 32 + lane];
            float vf[4]; CVT4(v, vf);
            #pragma unroll
            for (int i = 0; i < 4; ++i) acc[i] += w * vf[i];
        }
    }
    #pragma unroll
    for (int i = 0; i < 4; ++i) acc[i] *= di;
    ((float4*)&axs[rloc][lane * 4])[0] = make_float4(acc[0], acc[1], acc[2], acc[3]);
    __syncthreads();

    // ---- phase B: hs[q][t] = relu(sum_k axs[q][k] * W1[k][t] + b1[t]); t = column
    float hacc[8];
    #pragma unroll
    for (int q = 0; q < 8; ++q) hacc[q] = 0.0f;
    #pragma unroll 4
    for (int k = 0; k < NFEAT; ++k) {
        float w = W1[k * NHID + t];
        #pragma unroll
        for (int q = 0; q < 8; ++q) hacc[q] += axs[q][k] * w;
    }
    float bb = b1[t];
    #pragma unroll
    for (int q = 0; q < 8; ++q) {
        float v = hacc[q] + bb;
        hs[q][t] = v > 0.0f ? v : 0.0f;
    }
    __syncthreads();

    // ---- phase C: V2s[r][j] = dinv[r] * sum_k hs[r][k] * W2[k][j]; W2 via L1/L2
    int j = t & 15;
    int rq = (t >> 4) & 7;
    int kb = (t >> 7) * 128;
    float p = 0.0f;
    #pragma unroll 8
    for (int k = 0; k < 128; ++k) p += hs[rq][kb + k] * W2[(kb + k) * NCLASS + j];
    part[t] = p;
    __syncthreads();
    if (t < 128) {
        int rg = blockIdx.x * 8 + (t >> 4);
        V2s[rg * NCLASS + (t & 15)] = dinv[rg] * (part[t] + part[t + 128]);
    }
}

// ---------------- out[r] = log_softmax(dinv[r]*(V2s[r] + sum w*V2s[c]) + b2) ----------------
// V2s already carries di[c]; weights RAW here.
__global__ __launch_bounds__(256) void agg2_kernel(const int* __restrict__ cnt,
                                                   const int2* __restrict__ ell,
                                                   const float* __restrict__ V2s,
                                                   const float* __restrict__ dinv,
                                                   const float* __restrict__ b2,
                                                   float* __restrict__ out) {
    int t = threadIdx.x;
    int j = t & 15;                   // class
    int r = blockIdx.x * 16 + (t >> 4);
    int n = cnt[r];
    float di = dinv[r];
    float acc = V2s[r * NCLASS + j];  // self term (V2s already dinv-scaled)
    for (int base = 0; base < n; base += 16) {
        int idx = base + j;
        int2 cw = ell[r * ELLS + idx];
        int cc = cw.x & (N_NODES - 1);
        float wl = __int_as_float(cw.y);
        wl = (idx < n) ? wl : 0.0f;
        #pragma unroll
        for (int u = 0; u < 16; ++u) {
            int c = __shfl(cc, u, 16);
            float w = __shfl(wl, u, 16);
            acc += w * V2s[c * NCLASS + j];
        }
    }
    float v = di * acc + b2[j];
    // log_softmax across the 16 lanes of this row-group
    float mx = v;
    #pragma unroll
    for (int off = 1; off < 16; off <<= 1) mx = fmaxf(mx, __shfl_xor(mx, off));
    float ex = expf(v - mx);
    float ssum = ex;
    #pragma unroll
    for (int off = 1; off < 16; off <<= 1) ssum += __shfl_xor(ssum, off);
    out[r * NCLASS + j] = v - mx - logf(ssum);
}

extern "C" void kernel_launch(void* const* d_in, const int* in_sizes, int n_in,
                              void* d_out, int out_size, void* d_ws, size_t ws_size,
                              hipStream_t stream) {
    const float* x  = (const float*)d_in[0];
    const int*   ei = (const int*)d_in[1];      // [2, E] flat: row = ei[e], col = ei[E+e]
    const float* ew = (const float*)d_in[2];
    const float* W1 = (const float*)d_in[3];
    const float* b1 = (const float*)d_in[4];
    const float* W2 = (const float*)d_in[5];
    const float* b2 = (const float*)d_in[6];
    float* out = (float*)d_out;

    const int n = N_NODES;

    char* ws = (char*)d_ws;
    int*   cnt  = (int*)  (ws);                  // [0, 32K)
    float* dinv = (float*)(ws + 32768);          // [32K, 64K)
    int2*  ell  = (int2*) (ws + 65536);          // [64K, 64K+6M): 8192*96*8 B
    float* V2s  = (float*)(ws + 8388608);        // [8M, 8.5M)
    uint4* xs   = (uint4*)(ws + 16777216);       // [16M, 18M): bf16 dinv-scaled x

    zero_kernel<<<32, 256, 0, stream>>>(cnt);

    histscatter_kernel<<<N_EDGES / 256, 256, 0, stream>>>(ei, ew, cnt, ell);
    dinvcvt_kernel<<<n / 16, 256, 0, stream>>>(cnt, ell, x, dinv, xs);

    layer12_kernel<<<n / 8, 256, 0, stream>>>(cnt, ell, (const uint2*)xs,
                                              dinv, W1, b1, W2, V2s);
    agg2_kernel<<<n / 16, 256, 0, stream>>>(cnt, ell, V2s, dinv, b2, out);
}